// Round 1
// baseline (151.907 us; speedup 1.0000x reference)
//
#include <hip/hip_runtime.h>
#include <math.h>

// NaiveDFTQNN: 25-wire state vector, DIM = 2^25.
// out = (cos(theta0/2)/||f||) * (tensor product of 12 Givens rotations) * f
// Pair j (j=0..11) acts on little-endian bits (2j+1, 2j) with angle theta[11-j]/2:
//   v=0b01: n1 = c*a1 - s*a2 ; v=0b10: n2 = s*a1 + c*a2 ; v=00,11 untouched.
// Bit 24 (wire 0) is a spectator (RX folds into the scalar).

#define DIM_LOG 25

// LDS bank swizzles: flip float-index bits 2..4 (16B-block slot) by higher bits so
// every pass's b128 access pattern spreads over all 8 bank-groups. 4-aligned
// blocks stay intact -> float4 LDS ops with static component indexing.
static __device__ __forceinline__ int swzK1(int i) { return i ^ (((i >> 8) & 7) << 2); }
static __device__ __forceinline__ int swzK3(int i) { return i ^ ((((i >> 6) ^ (i >> 10)) & 7) << 2); }

static __device__ __forceinline__ void rot4(float4& a, float4& b, float c, float s) {
    float4 na, nb;
    na.x = c * a.x - s * b.x;  nb.x = s * a.x + c * b.x;
    na.y = c * a.y - s * b.y;  nb.y = s * a.y + c * b.y;
    na.z = c * a.z - s * b.z;  nb.z = s * a.z + c * b.z;
    na.w = c * a.w - s * b.w;  nb.w = s * a.w + c * b.w;
    a = na; b = nb;
}

// ---------------- K1: high pairs (bits 14..23), in -> out, + norm partials ---------
__global__ __launch_bounds__(256) void qnn_high(const float* __restrict__ in,
                                                const float* __restrict__ theta,
                                                float* __restrict__ out,
                                                double* __restrict__ partials) {
    __shared__ __align__(16) float lds[16384];
    const int t = threadIdx.x;
    // XCD-aware swizzle (2048 % 8 == 0 -> bijective): each XCD gets 256
    // consecutive logical ids so adjacent low-chunks (sharing 128B lines)
    // stay on one XCD's L2.
    const int blk = blockIdx.x;
    const int logical = (blk & 7) * 256 + (blk >> 3);
    const int chunk = logical & 1023;       // low-14-bit chunk (16 floats each)
    const int b24 = logical >> 10;          // spectator bit 24
    const long base = ((long)b24 << 24) | ((long)chunk << 4);

    // pairs jj=0..4 <-> bit pairs (15,14)..(23,22) <-> theta[4-jj]
    float c0, s0, c1, s1, c2, s2, c3, s3, c4, s4;
    {
        float th;
        th = 0.5f * theta[4]; c0 = cosf(th); s0 = sinf(th);
        th = 0.5f * theta[3]; c1 = cosf(th); s1 = sinf(th);
        th = 0.5f * theta[2]; c2 = cosf(th); s2 = sinf(th);
        th = 0.5f * theta[1]; c3 = cosf(th); s3 = sinf(th);
        th = 0.5f * theta[0]; c4 = cosf(th); s4 = sinf(th);
    }

    double acc = 0.0;
    // load tile: h = high-combo (10 bits), payload = 16 floats (4 float4 slots)
#pragma unroll
    for (int k = 0; k < 16; ++k) {
        int w = k * 256 + t;
        int p = (w & 3) << 2;
        int h = w >> 2;
        float4 v = *(const float4*)(in + base + ((long)h << 14) + p);
        acc += (double)v.x * v.x + (double)v.y * v.y + (double)v.z * v.z + (double)v.w * v.w;
        *(float4*)&lds[swzK1((h << 4) | p)] = v;
    }
    __syncthreads();

    // pass A: pairs at h bits (1,0) [theta4] and (3,2) [theta3]
    {
        const int p = (t & 3) << 2;
        const int m = t >> 2;  // [0,64): h bits 4..9
        float4 f[4][4];
#pragma unroll
        for (int vB = 0; vB < 4; ++vB)
#pragma unroll
            for (int vA = 0; vA < 4; ++vA)
                f[vB][vA] = *(float4*)&lds[swzK1((((m << 4) | (vB << 2) | vA) << 4) | p)];
#pragma unroll
        for (int vB = 0; vB < 4; ++vB) rot4(f[vB][1], f[vB][2], c0, s0);
#pragma unroll
        for (int vA = 0; vA < 4; ++vA) rot4(f[1][vA], f[2][vA], c1, s1);
#pragma unroll
        for (int vB = 0; vB < 4; ++vB)
#pragma unroll
            for (int vA = 0; vA < 4; ++vA)
                *(float4*)&lds[swzK1((((m << 4) | (vB << 2) | vA) << 4) | p)] = f[vB][vA];
    }
    __syncthreads();

    // pass B: pairs at h bits (5,4) [theta2] and (7,6) [theta1]
    {
        const int p = (t & 3) << 2;
        const int m = t >> 2;
        const int hl = m & 15, hh = m >> 4;
        float4 f[4][4];
#pragma unroll
        for (int vB = 0; vB < 4; ++vB)
#pragma unroll
            for (int vA = 0; vA < 4; ++vA)
                f[vB][vA] = *(float4*)&lds[swzK1((((hh << 8) | (vB << 6) | (vA << 4) | hl) << 4) | p)];
#pragma unroll
        for (int vB = 0; vB < 4; ++vB) rot4(f[vB][1], f[vB][2], c2, s2);
#pragma unroll
        for (int vA = 0; vA < 4; ++vA) rot4(f[1][vA], f[2][vA], c3, s3);
#pragma unroll
        for (int vB = 0; vB < 4; ++vB)
#pragma unroll
            for (int vA = 0; vA < 4; ++vA)
                *(float4*)&lds[swzK1((((hh << 8) | (vB << 6) | (vA << 4) | hl) << 4) | p)] = f[vB][vA];
    }
    __syncthreads();

    // pass C: pair at h bits (9,8) [theta0]
#pragma unroll
    for (int k = 0; k < 4; ++k) {
        int g = k * 256 + t;
        int p = (g & 3) << 2;
        int m = g >> 2;  // [0,256): h bits 0..7
        float4 a = *(float4*)&lds[swzK1((((1 << 8) | m) << 4) | p)];
        float4 b = *(float4*)&lds[swzK1((((2 << 8) | m) << 4) | p)];
        rot4(a, b, c4, s4);
        *(float4*)&lds[swzK1((((1 << 8) | m) << 4) | p)] = a;
        *(float4*)&lds[swzK1((((2 << 8) | m) << 4) | p)] = b;
    }
    __syncthreads();

    // store tile
#pragma unroll
    for (int k = 0; k < 16; ++k) {
        int w = k * 256 + t;
        int p = (w & 3) << 2;
        int h = w >> 2;
        float4 v = *(float4*)&lds[swzK1((h << 4) | p)];
        *(float4*)(out + base + ((long)h << 14) + p) = v;
    }

    // block-reduce sum of squares (deterministic; reuse LDS after all reads done)
#pragma unroll
    for (int off = 32; off > 0; off >>= 1) acc += __shfl_down(acc, off);
    __syncthreads();
    if ((t & 63) == 0) ((double*)lds)[t >> 6] = acc;
    __syncthreads();
    if (t == 0) {
        double* dl = (double*)lds;
        partials[blk] = dl[0] + dl[1] + dl[2] + dl[3];
    }
}

// ---------------- K2: reduce partials -> scale = cos(theta0/2)/sqrt(sum) ----------
__global__ void qnn_norm(const double* __restrict__ partials,
                         const float* __restrict__ theta,
                         double* __restrict__ scale) {
    __shared__ double w[4];
    const int t = threadIdx.x;
    double acc = 0.0;
    for (int i = t; i < 2048; i += 256) acc += partials[i];
#pragma unroll
    for (int off = 32; off > 0; off >>= 1) acc += __shfl_down(acc, off);
    if ((t & 63) == 0) w[t >> 6] = acc;
    __syncthreads();
    if (t == 0) {
        double tot = w[0] + w[1] + w[2] + w[3];
        *scale = (double)cosf(0.5f * theta[0]) / sqrt(tot);
    }
}

// ---------------- K3: low pairs (bits 0..13) + scale, in-place on out -------------
__global__ __launch_bounds__(256) void qnn_low(float* __restrict__ buf,
                                               const float* __restrict__ theta,
                                               const double* __restrict__ scale) {
    __shared__ __align__(16) float lds[16384];
    const int t = threadIdx.x;
    const long base = (long)blockIdx.x << 14;
    // pair j (bits 2j+1,2j) -> theta[11-j], j=0..6
    float cj[7], sj[7];
#pragma unroll
    for (int j = 0; j < 7; ++j) {
        float th = 0.5f * theta[11 - j];
        cj[j] = cosf(th); sj[j] = sinf(th);
    }
    const float sc = (float)(*scale);

    // phase 1: 64 contiguous floats/thread; pairs j=0,1,2 (bits 0..5) in registers
    float4 r[16];
#pragma unroll
    for (int q = 0; q < 16; ++q) r[q] = *(const float4*)(buf + base + (t << 6) + (q << 2));
    // j=0: bits (1,0) = float4 components 1,2
#pragma unroll
    for (int q = 0; q < 16; ++q) {
        float n1 = cj[0] * r[q].y - sj[0] * r[q].z;
        float n2 = sj[0] * r[q].y + cj[0] * r[q].z;
        r[q].y = n1; r[q].z = n2;
    }
    // j=1: bits (3,2) = q bits (1,0)
#pragma unroll
    for (int qh = 0; qh < 4; ++qh) rot4(r[(qh << 2) | 1], r[(qh << 2) | 2], cj[1], sj[1]);
    // j=2: bits (5,4) = q bits (3,2)
#pragma unroll
    for (int ql = 0; ql < 4; ++ql) rot4(r[4 | ql], r[8 | ql], cj[2], sj[2]);
#pragma unroll
    for (int q = 0; q < 16; ++q) *(float4*)&lds[swzK3((t << 6) | (q << 2))] = r[q];
    __syncthreads();

    // pass: pairs at elem bits (7,6) [theta8] and (9,8) [theta7]; rows = bits 6..13
    {
        const int p = (t & 15) << 2;   // payload float4 slot (bits 0..5)
        const int res = t >> 4;        // row bits 4..7 (elem bits 10..13)
        float4 f[4][4];
#pragma unroll
        for (int vB = 0; vB < 4; ++vB)
#pragma unroll
            for (int vA = 0; vA < 4; ++vA)
                f[vB][vA] = *(float4*)&lds[swzK3((((res << 4) | (vB << 2) | vA) << 6) | p)];
#pragma unroll
        for (int vB = 0; vB < 4; ++vB) rot4(f[vB][1], f[vB][2], cj[3], sj[3]);
#pragma unroll
        for (int vA = 0; vA < 4; ++vA) rot4(f[1][vA], f[2][vA], cj[4], sj[4]);
#pragma unroll
        for (int vB = 0; vB < 4; ++vB)
#pragma unroll
            for (int vA = 0; vA < 4; ++vA)
                *(float4*)&lds[swzK3((((res << 4) | (vB << 2) | vA) << 6) | p)] = f[vB][vA];
    }
    __syncthreads();

    // pass: pairs at elem bits (11,10) [theta6] and (13,12) [theta5]
    {
        const int p = (t & 15) << 2;
        const int res = t >> 4;        // row bits 0..3 (elem bits 6..9)
        float4 f[4][4];
#pragma unroll
        for (int vB = 0; vB < 4; ++vB)
#pragma unroll
            for (int vA = 0; vA < 4; ++vA)
                f[vB][vA] = *(float4*)&lds[swzK3(((((vB << 2) | vA) << 4 | res) << 6) | p)];
#pragma unroll
        for (int vB = 0; vB < 4; ++vB) rot4(f[vB][1], f[vB][2], cj[5], sj[5]);
#pragma unroll
        for (int vA = 0; vA < 4; ++vA) rot4(f[1][vA], f[2][vA], cj[6], sj[6]);
#pragma unroll
        for (int vB = 0; vB < 4; ++vB)
#pragma unroll
            for (int vA = 0; vA < 4; ++vA)
                *(float4*)&lds[swzK3(((((vB << 2) | vA) << 4 | res) << 6) | p)] = f[vB][vA];
    }
    __syncthreads();

    // phase 3: scale + store
#pragma unroll
    for (int q = 0; q < 16; ++q) {
        float4 v = *(float4*)&lds[swzK3((t << 6) | (q << 2))];
        v.x *= sc; v.y *= sc; v.z *= sc; v.w *= sc;
        *(float4*)(buf + base + (t << 6) + (q << 2)) = v;
    }
}

extern "C" void kernel_launch(void* const* d_in, const int* in_sizes, int n_in,
                              void* d_out, int out_size, void* d_ws, size_t ws_size,
                              hipStream_t stream) {
    const float* in = (const float*)d_in[0];      // feature, 2^25 f32
    const float* theta = (const float*)d_in[1];   // 13 f32
    float* out = (float*)d_out;                   // 2^25 f32
    double* part = (double*)d_ws;                 // 2048 partials + 1 scale
    double* scale = part + 2048;

    qnn_high<<<2048, 256, 0, stream>>>(in, theta, out, part);
    qnn_norm<<<1, 256, 0, stream>>>(part, theta, scale);
    qnn_low<<<2048, 256, 0, stream>>>(out, theta, scale);
}